// Round 9
// baseline (40.459 us; speedup 1.0000x reference)
//
#include <hip/hip_runtime.h>

#define NB 32
#define TT 4096
#define DD 768
#define NJ 64
#define CHUNK 32
#define CPD (TT / CHUNK)          // 128 chunks per doc, grid 4096
#define NCLAUSES (NB * NJ)

typedef float f4 __attribute__((ext_vector_type(4)));
typedef float f2 __attribute__((ext_vector_type(2)));

__device__ __forceinline__ void dot_pair(
    const f4 h0, const f4 h1, const f4 h2,
    const f4 wf0, const f4 wf1, const f4 wf2,
    const f4 we0, const f4 we1, const f4 we2,
    float& pf, float& pe)
{
    pf = h0.x * wf0.x;
    pf = fmaf(h0.y, wf0.y, pf); pf = fmaf(h0.z, wf0.z, pf); pf = fmaf(h0.w, wf0.w, pf);
    pf = fmaf(h1.x, wf1.x, pf); pf = fmaf(h1.y, wf1.y, pf);
    pf = fmaf(h1.z, wf1.z, pf); pf = fmaf(h1.w, wf1.w, pf);
    pf = fmaf(h2.x, wf2.x, pf); pf = fmaf(h2.y, wf2.y, pf);
    pf = fmaf(h2.z, wf2.z, pf); pf = fmaf(h2.w, wf2.w, pf);

    pe = h0.x * we0.x;
    pe = fmaf(h0.y, we0.y, pe); pe = fmaf(h0.z, we0.z, pe); pe = fmaf(h0.w, we0.w, pe);
    pe = fmaf(h1.x, we1.x, pe); pe = fmaf(h1.y, we1.y, pe);
    pe = fmaf(h1.z, we1.z, pe); pe = fmaf(h1.w, we1.w, pe);
    pe = fmaf(h2.x, we2.x, pe); pe = fmaf(h2.y, we2.y, pe);
    pe = fmaf(h2.z, we2.z, pe); pe = fmaf(h2.w, we2.w, pe);
}

__device__ __forceinline__ void reduce_pair(float& pf, float& pe)
{
    #pragma unroll
    for (int s = 1; s < 64; s <<= 1) {
        pf += __shfl_xor(pf, s, 64);
        pe += __shfl_xor(pe, s, 64);
    }
}

// ---------------- Phase 1: per-token dual dot-products --------------------
// R5/R8 structure; results stored interleaved as float2 (one 8B store).
__global__ __launch_bounds__(256) void dots_kernel(
    const float* __restrict__ hs,         // [B, T, D]
    const int*   __restrict__ clause_len, // [B, J]
    const float* __restrict__ fc_w,       // [D]
    const float* __restrict__ emo_w,      // [D]
    f2*          __restrict__ ws)         // [B, T] {fc, emo}
{
    const int g     = blockIdx.x;
    const int b     = g & (NB - 1);
    const int chunk = g >> 5;
    const int lane  = threadIdx.x & 63;
    const int wave  = threadIdx.x >> 6;

    int L = clause_len[(b << 6) + lane];
    #pragma unroll
    for (int s = 1; s < 64; s <<= 1) L += __shfl_xor(L, s, 64);

    const int r0 = chunk * CHUNK + (wave << 3);   // 8 consecutive rows per wave
    const int nr = min(8, L - r0);
    if (nr <= 0) return;

    const f4* fw4 = (const f4*)fc_w;
    const f4* ew4 = (const f4*)emo_w;

    const f4* r4 = (const f4*)(hs + ((size_t)b * TT + r0) * DD);
    f2*       ow = ws + b * TT + r0;

    if (nr == 8) {
        f4 A[8][3];
        #pragma unroll
        for (int i = 0; i < 8; ++i) {
            const f4* p = r4 + i * 192;
            A[i][0] = p[lane];
            A[i][1] = p[lane + 64];
            A[i][2] = p[lane + 128];
        }
        const f4 wf0 = fw4[lane], wf1 = fw4[lane + 64], wf2 = fw4[lane + 128];
        const f4 we0 = ew4[lane], we1 = ew4[lane + 64], we2 = ew4[lane + 128];
        #pragma unroll
        for (int i = 0; i < 8; ++i) {
            float pf, pe;
            dot_pair(A[i][0], A[i][1], A[i][2], wf0, wf1, wf2, we0, we1, we2, pf, pe);
            reduce_pair(pf, pe);
            if (lane == 0) { f2 v; v.x = pf; v.y = pe; ow[i] = v; }
        }
    } else {
        const f4 wf0 = fw4[lane], wf1 = fw4[lane + 64], wf2 = fw4[lane + 128];
        const f4 we0 = ew4[lane], we1 = ew4[lane + 64], we2 = ew4[lane + 128];
        for (int i = 0; i < nr; ++i) {
            const f4* p = r4 + i * 192;
            const f4 a0 = p[lane], a1 = p[lane + 64], a2 = p[lane + 128];
            float pf, pe;
            dot_pair(a0, a1, a2, wf0, wf1, wf2, we0, we1, we2, pf, pe);
            reduce_pair(pf, pe);
            if (lane == 0) { f2 v; v.x = pf; v.y = pe; ow[i] = v; }
        }
    }
}

// ---------------- Phase 2: per-clause softmax + sigmoid -------------------
__global__ __launch_bounds__(256) void pool_kernel(
    const int*   __restrict__ clause_len, // [B, J]
    const f2*    __restrict__ ws,         // [B, T] {fc, emo}
    const float* __restrict__ fc_b,       // [1]
    const float* __restrict__ emo_b,      // [1]
    float*       __restrict__ out)        // [B, J]
{
    const int lane = threadIdx.x & 63;
    const int wave = threadIdx.x >> 6;
    const int bj   = (blockIdx.x << 2) + wave;
    const int b    = bj >> 6;
    const int j    = bj & 63;

    const float fcb = fc_b[0];           // issue scalar loads first
    const float emb = emo_b[0];

    const int cl   = clause_len[(b << 6) + lane];
    const int clen = __shfl(cl, j, 64);
    int pre = (lane < j) ? cl : 0;
    #pragma unroll
    for (int s = 1; s < 64; s <<= 1) pre += __shfl_xor(pre, s, 64);
    const int start = pre;

    const bool valid = lane < clen;
    const int  t     = b * TT + start + lane;
    f2 d;
    d.x = 0.0f; d.y = 0.0f;
    if (valid) d = ws[t];

    float v   = valid ? (d.x + fcb) : -3.0e38f;
    float m = v;
    #pragma unroll
    for (int s = 1; s < 64; s <<= 1) m = fmaxf(m, __shfl_xor(m, s, 64));
    const float e = valid ? __expf(v - m) : 0.0f;
    float Z = e, S = e * d.y;
    #pragma unroll
    for (int s = 1; s < 64; s <<= 1) {
        Z += __shfl_xor(Z, s, 64);
        S += __shfl_xor(S, s, 64);
    }
    if (lane == 0) {
        const float logit = S / Z + emb;
        out[bj] = 1.0f / (1.0f + __expf(-logit));
    }
}

extern "C" void kernel_launch(void* const* d_in, const int* in_sizes, int n_in,
                              void* d_out, int out_size, void* d_ws, size_t ws_size,
                              hipStream_t stream) {
    const float* hs         = (const float*)d_in[0];
    const int*   clause_len = (const int*)d_in[1];
    const float* fc_w       = (const float*)d_in[2];
    const float* fc_b       = (const float*)d_in[3];
    const float* emo_w      = (const float*)d_in[4];
    const float* emo_b      = (const float*)d_in[5];
    float* out = (float*)d_out;

    f2* ws = (f2*)d_ws;                  // [B*T] interleaved {fc, emo}

    dots_kernel<<<NB * CPD, 256, 0, stream>>>(
        hs, clause_len, fc_w, emo_w, ws);
    pool_kernel<<<NCLAUSES / 4, 256, 0, stream>>>(
        clause_len, ws, fc_b, emo_b, out);
}

// Round 10
// 39.485 us; speedup vs baseline: 1.0247x; 1.0247x over previous
//
#include <hip/hip_runtime.h>

#define NB 32
#define TT 4096
#define DD 768
#define NJ 64
#define CHUNK 32
#define CPD (TT / CHUNK)          // 128 chunks per doc, grid 4096
#define NCLAUSES (NB * NJ)

typedef float f4 __attribute__((ext_vector_type(4)));

__device__ __forceinline__ void dot_pair(
    const f4 h0, const f4 h1, const f4 h2,
    const f4 wf0, const f4 wf1, const f4 wf2,
    const f4 we0, const f4 we1, const f4 we2,
    float& pf, float& pe)
{
    pf = h0.x * wf0.x;
    pf = fmaf(h0.y, wf0.y, pf); pf = fmaf(h0.z, wf0.z, pf); pf = fmaf(h0.w, wf0.w, pf);
    pf = fmaf(h1.x, wf1.x, pf); pf = fmaf(h1.y, wf1.y, pf);
    pf = fmaf(h1.z, wf1.z, pf); pf = fmaf(h1.w, wf1.w, pf);
    pf = fmaf(h2.x, wf2.x, pf); pf = fmaf(h2.y, wf2.y, pf);
    pf = fmaf(h2.z, wf2.z, pf); pf = fmaf(h2.w, wf2.w, pf);

    pe = h0.x * we0.x;
    pe = fmaf(h0.y, we0.y, pe); pe = fmaf(h0.z, we0.z, pe); pe = fmaf(h0.w, we0.w, pe);
    pe = fmaf(h1.x, we1.x, pe); pe = fmaf(h1.y, we1.y, pe);
    pe = fmaf(h1.z, we1.z, pe); pe = fmaf(h1.w, we1.w, pe);
    pe = fmaf(h2.x, we2.x, pe); pe = fmaf(h2.y, we2.y, pe);
    pe = fmaf(h2.z, we2.z, pe); pe = fmaf(h2.w, we2.w, pe);
}

__device__ __forceinline__ void reduce_pair(float& pf, float& pe)
{
    #pragma unroll
    for (int s = 1; s < 64; s <<= 1) {
        pf += __shfl_xor(pf, s, 64);
        pe += __shfl_xor(pe, s, 64);
    }
}

// ---------------- Phase 1: per-token dual dot-products --------------------
// R8 structure (CHUNK=32, 8 rows/wave, prefetch-all), but the per-row
// butterfly reduce (12 shfl/row, 48-step dep chain per wave-iter) is
// replaced by ONE multi-value fold-reduce: 17 shuffles per 8 rows, 6-step
// dep chain. Final value index i = bits[5:2] of lane (row=i>>1, fc/emo=i&1).
__global__ __launch_bounds__(256) void dots_kernel(
    const float* __restrict__ hs,         // [B, T, D]
    const int*   __restrict__ clause_len, // [B, J]
    const float* __restrict__ fc_w,       // [D]
    const float* __restrict__ emo_w,      // [D]
    float*       __restrict__ ws_fc,      // [B, T]
    float*       __restrict__ ws_emo)     // [B, T]
{
    const int g     = blockIdx.x;
    const int b     = g & (NB - 1);
    const int chunk = g >> 5;
    const int lane  = threadIdx.x & 63;
    const int wave  = threadIdx.x >> 6;

    int L = clause_len[(b << 6) + lane];
    #pragma unroll
    for (int s = 1; s < 64; s <<= 1) L += __shfl_xor(L, s, 64);

    const int r0 = chunk * CHUNK + (wave << 3);   // 8 consecutive rows per wave
    const int nr = min(8, L - r0);
    if (nr <= 0) return;

    const f4* fw4 = (const f4*)fc_w;
    const f4* ew4 = (const f4*)emo_w;

    const f4* r4  = (const f4*)(hs + ((size_t)b * TT + r0) * DD);
    float*    ofc = ws_fc  + b * TT + r0;
    float*    oem = ws_emo + b * TT + r0;

    if (nr == 8) {
        f4 A[8][3];
        #pragma unroll
        for (int i = 0; i < 8; ++i) {
            const f4* p = r4 + i * 192;
            A[i][0] = p[lane];
            A[i][1] = p[lane + 64];
            A[i][2] = p[lane + 128];
        }
        const f4 wf0 = fw4[lane], wf1 = fw4[lane + 64], wf2 = fw4[lane + 128];
        const f4 we0 = ew4[lane], we1 = ew4[lane + 64], we2 = ew4[lane + 128];

        float v[16];                       // v[2r]=pf_r, v[2r+1]=pe_r
        #pragma unroll
        for (int i = 0; i < 8; ++i) {
            float pf, pe;
            dot_pair(A[i][0], A[i][1], A[i][2], wf0, wf1, wf2, we0, we1, we2, pf, pe);
            v[2 * i]     = pf;
            v[2 * i + 1] = pe;
        }

        // fold-reduce: 16 values x 64 lanes -> 16 scalars, 17 shuffles total
        #pragma unroll
        for (int k = 0; k < 8; ++k) {      // mask 32: 16 -> 8 live values
            const float s = (lane & 32) ? v[k] : v[k + 8];
            const float r = __shfl_xor(s, 32, 64);
            v[k] = ((lane & 32) ? v[k + 8] : v[k]) + r;
        }
        #pragma unroll
        for (int k = 0; k < 4; ++k) {      // mask 16: 8 -> 4
            const float s = (lane & 16) ? v[k] : v[k + 4];
            const float r = __shfl_xor(s, 16, 64);
            v[k] = ((lane & 16) ? v[k + 4] : v[k]) + r;
        }
        #pragma unroll
        for (int k = 0; k < 2; ++k) {      // mask 8: 4 -> 2
            const float s = (lane & 8) ? v[k] : v[k + 2];
            const float r = __shfl_xor(s, 8, 64);
            v[k] = ((lane & 8) ? v[k + 2] : v[k]) + r;
        }
        {                                  // mask 4: 2 -> 1
            const float s = (lane & 4) ? v[0] : v[1];
            const float r = __shfl_xor(s, 4, 64);
            v[0] = ((lane & 4) ? v[1] : v[0]) + r;
        }
        v[0] += __shfl_xor(v[0], 2, 64);   // reduce across the quad
        v[0] += __shfl_xor(v[0], 1, 64);

        if ((lane & 3) == 0) {
            const int i = lane >> 2;       // 0..15; row = i>>1, fc/emo = i&1
            if (i & 1) oem[i >> 1] = v[0];
            else       ofc[i >> 1] = v[0];
        }
    } else {
        const f4 wf0 = fw4[lane], wf1 = fw4[lane + 64], wf2 = fw4[lane + 128];
        const f4 we0 = ew4[lane], we1 = ew4[lane + 64], we2 = ew4[lane + 128];
        for (int i = 0; i < nr; ++i) {
            const f4* p = r4 + i * 192;
            const f4 a0 = p[lane], a1 = p[lane + 64], a2 = p[lane + 128];
            float pf, pe;
            dot_pair(a0, a1, a2, wf0, wf1, wf2, we0, we1, we2, pf, pe);
            reduce_pair(pf, pe);
            if (lane == 0) { ofc[i] = pf; oem[i] = pe; }
        }
    }
}

// ---------------- Phase 2: per-clause softmax + sigmoid -------------------
__global__ __launch_bounds__(256) void pool_kernel(
    const int*   __restrict__ clause_len, // [B, J]
    const float* __restrict__ ws_fc,      // [B, T]
    const float* __restrict__ ws_emo,     // [B, T]
    const float* __restrict__ fc_b,       // [1]
    const float* __restrict__ emo_b,      // [1]
    float*       __restrict__ out)        // [B, J]
{
    const int lane = threadIdx.x & 63;
    const int wave = threadIdx.x >> 6;
    const int bj   = (blockIdx.x << 2) + wave;
    const int b    = bj >> 6;
    const int j    = bj & 63;

    const float fcb = fc_b[0];
    const float emb = emo_b[0];

    const int cl   = clause_len[(b << 6) + lane];
    const int clen = __shfl(cl, j, 64);
    int pre = (lane < j) ? cl : 0;
    #pragma unroll
    for (int s = 1; s < 64; s <<= 1) pre += __shfl_xor(pre, s, 64);
    const int start = pre;

    const bool valid = lane < clen;
    const int  t     = b * TT + start + lane;
    float v   = valid ? (ws_fc[t] + fcb) : -3.0e38f;
    float sem = valid ? ws_emo[t] : 0.0f;
    float m = v;
    #pragma unroll
    for (int s = 1; s < 64; s <<= 1) m = fmaxf(m, __shfl_xor(m, s, 64));
    const float e = valid ? __expf(v - m) : 0.0f;
    float Z = e, S = e * sem;
    #pragma unroll
    for (int s = 1; s < 64; s <<= 1) {
        Z += __shfl_xor(Z, s, 64);
        S += __shfl_xor(S, s, 64);
    }
    if (lane == 0) {
        const float logit = S / Z + emb;
        out[bj] = 1.0f / (1.0f + __expf(-logit));
    }
}

extern "C" void kernel_launch(void* const* d_in, const int* in_sizes, int n_in,
                              void* d_out, int out_size, void* d_ws, size_t ws_size,
                              hipStream_t stream) {
    const float* hs         = (const float*)d_in[0];
    const int*   clause_len = (const int*)d_in[1];
    const float* fc_w       = (const float*)d_in[2];
    const float* fc_b       = (const float*)d_in[3];
    const float* emo_w      = (const float*)d_in[4];
    const float* emo_b      = (const float*)d_in[5];
    float* out = (float*)d_out;

    float* ws_fc  = (float*)d_ws;            // [B*T]
    float* ws_emo = ws_fc + NB * TT;         // [B*T]

    dots_kernel<<<NB * CPD, 256, 0, stream>>>(
        hs, clause_len, fc_w, emo_w, ws_fc, ws_emo);
    pool_kernel<<<NCLAUSES / 4, 256, 0, stream>>>(
        clause_len, ws_fc, ws_emo, fc_b, emo_b, out);
}